// Round 6
// baseline (561.639 us; speedup 1.0000x reference)
//
#include <hip/hip_runtime.h>

// LSTM T=1024, B=2048, INPUT=2, H=64 — MFMA recurrence.
// R5: BB=4 batch/block, 512 blocks -> 2 independent blocks/CU (2 waves/SIMD)
// so co-resident blocks hide each other's barrier/LDS/trans latency.
// MFMA N-cols 4..15 duplicate 0..3; each lane owns exactly 1 (h,b) state
// (eh = bcol>>2 selects the D element) -> 10 trans ops/lane/step.
// h-table stride 80 shorts: ds_read_b128 quads tile banks exactly 2-way
// (free), b16 writes 2-per-dword (free). One barrier/step, double-buffered.
// Numerics: bf16 hi/lo split W_hh, fresh-rounded bf16 h, fp32 c (as R2-R4).

typedef short bf16x8 __attribute__((ext_vector_type(8)));
typedef float f32x4  __attribute__((ext_vector_type(4)));

constexpr int T_STEPS = 1024;
constexpr int BATCH   = 2048;
constexpr int H       = 64;
constexpr int BB      = 4;      // batch per block
constexpr int THREADS = 256;    // 4 waves
constexpr int HSTR    = 80;     // bf16 per batch row (160B; 40 dwords -> 2-way banks)

__device__ __forceinline__ unsigned bf16_rn(float f) {
    unsigned u = __float_as_uint(f);
    u += 0x7fffu + ((u >> 16) & 1u);
    return u >> 16;
}
__device__ __forceinline__ float bf16_f(unsigned h) {
    return __uint_as_float(h << 16);
}
__device__ __forceinline__ float sigm(float v) {
    return __builtin_amdgcn_rcpf(1.0f + __builtin_amdgcn_exp2f(v * -1.44269504f));
}
__device__ __forceinline__ float tanh_(float v) {
    return fmaf(-2.0f, __builtin_amdgcn_rcpf(1.0f + __builtin_amdgcn_exp2f(v * 2.88539008f)), 1.0f);
}

__global__ __launch_bounds__(THREADS, 2) void lstm_mfma2(
    const float* __restrict__ x,      // (T, B, 2)
    const float* __restrict__ W_ih,   // (256, 2)
    const float* __restrict__ W_hh,   // (256, 64)
    const float* __restrict__ b_ih,   // (256)
    const float* __restrict__ b_hh,   // (256)
    const float* __restrict__ W_fc,   // (1, 64)
    const float* __restrict__ b_fc,   // (1)
    float* __restrict__ out)          // (B, 1)
{
    const int tid  = threadIdx.x;
    const int w    = tid >> 6;        // wave 0..3: h-slice [16w, 16w+16)
    const int lane = tid & 63;
    const int bcol = lane & 15;       // MFMA column
    const int grp  = lane >> 4;       // k-group / D-row group
    const int bloc = bcol & 3;        // real batch (cols 4..15 duplicate 0..3)
    const int eh   = bcol >> 2;       // which D element this lane activates

    __shared__ __align__(16) unsigned short s_ht[2][BB * HSTR]; // 2 x 640 B
    __shared__ float s_red[16];

    const int b0 = blockIdx.x * BB;

    // ---- A fragments: gate g tile = W_hh rows [64g+16w, +16), hi/lo bf16 --
    bf16x8 Ahi[4][2], Alo[4][2];
    #pragma unroll
    for (int g = 0; g < 4; ++g) {
        #pragma unroll
        for (int kk = 0; kk < 2; ++kk) {
            const float* src = W_hh + (64 * g + 16 * w + bcol) * H + kk * 32 + grp * 8;
            #pragma unroll
            for (int j = 0; j < 8; ++j) {
                const float v = src[j];
                const unsigned hi = bf16_rn(v);
                const unsigned lo = bf16_rn(v - bf16_f(hi));
                Ahi[g][kk][j] = (short)hi;
                Alo[g][kk][j] = (short)lo;
            }
        }
    }

    // ---- gx constants: D row (gate g) = 64g + 16w + 4grp + e --------------
    float gb[4][4], c0_[4][4], c1_[4][4];
    #pragma unroll
    for (int g = 0; g < 4; ++g)
        #pragma unroll
        for (int e = 0; e < 4; ++e) {
            const int r = 64 * g + 16 * w + 4 * grp + e;
            gb[g][e]  = b_ih[r] + b_hh[r];
            c0_[g][e] = W_ih[2 * r];
            c1_[g][e] = W_ih[2 * r + 1];
        }

    // ---- per-lane state: h-row rbase of batch b0+bloc ---------------------
    const int rbase = 16 * w + 4 * grp + eh;
    float cs = 0.f, hv = 0.f;
    const float wfc = W_fc[rbase];

    // zero both h-table buffers (2*4*80 shorts = 320 dwords)
    for (int i = tid; i < 320; i += THREADS)
        reinterpret_cast<unsigned*>(s_ht)[i] = 0;

    // ---- x: depth-2 register prefetch (dup lanes load same addr) ----------
    const float* xb = x + (b0 + bloc) * 2;
    float2 xc  = *reinterpret_cast<const float2*>(xb);
    float2 xn1 = *reinterpret_cast<const float2*>(xb + 1 * BATCH * 2);
    float2 xn2 = *reinterpret_cast<const float2*>(xb + 2 * BATCH * 2);

    __syncthreads();

    // initial B fragments from buf 0 (h = 0); single b128 per kk
    bf16x8 Bf[2];
    #pragma unroll
    for (int kk = 0; kk < 2; ++kk)
        Bf[kk] = *reinterpret_cast<const bf16x8*>(
                     &s_ht[0][bloc * HSTR + kk * 32 + grp * 8]);

    #pragma unroll 2
    for (int s = 0; s < T_STEPS; ++s) {
        // acc init = gx (exact fp32; valid for every e at this lane's bloc)
        f32x4 acc[4];
        #pragma unroll
        for (int g = 0; g < 4; ++g)
            #pragma unroll
            for (int e = 0; e < 4; ++e)
                acc[g][e] = fmaf(c1_[g][e], xc.y, fmaf(c0_[g][e], xc.x, gb[g][e]));

        // recurrent GEMM: 4 gate-chains of 4 dependent MFMAs, interleaved
        #pragma unroll
        for (int kk = 0; kk < 2; ++kk) {
            #pragma unroll
            for (int g = 0; g < 4; ++g)
                acc[g] = __builtin_amdgcn_mfma_f32_16x16x32_bf16(Ahi[g][kk], Bf[kk], acc[g], 0, 0, 0);
            #pragma unroll
            for (int g = 0; g < 4; ++g)
                acc[g] = __builtin_amdgcn_mfma_f32_16x16x32_bf16(Alo[g][kk], Bf[kk], acc[g], 0, 0, 0);
        }

        // select this lane's single state (4x column duplication)
        float p[4];
        #pragma unroll
        for (int g = 0; g < 4; ++g) {
            const float v01 = (eh & 1) ? acc[g][1] : acc[g][0];
            const float v23 = (eh & 1) ? acc[g][3] : acc[g][2];
            p[g] = (eh & 2) ? v23 : v01;
        }

        // activations + c/h update, fully in-register (10 trans ops)
        {
            const float iv = sigm(p[0]), fv = sigm(p[1]);
            const float gv = tanh_(p[2]), ov = sigm(p[3]);
            cs = fmaf(fv, cs, iv * gv);
            hv = ov * tanh_(cs);
        }

        // h -> bf16, one b16 write to next-parity table (2-per-dword, free)
        s_ht[(s + 1) & 1][bloc * HSTR + rbase] = (unsigned short)bf16_rn(hv);

        // rotate x prefetch (depth 2)
        xc = xn1; xn1 = xn2;
        const int sn = (s + 3 < T_STEPS) ? s + 3 : T_STEPS - 1;
        xn2 = *reinterpret_cast<const float2*>(xb + sn * BATCH * 2);

        __syncthreads();   // next-parity h-table visible

        // B fragments for next step: b128 quads tile banks exactly 2-way
        #pragma unroll
        for (int kk = 0; kk < 2; ++kk)
            Bf[kk] = *reinterpret_cast<const bf16x8*>(
                         &s_ht[(s + 1) & 1][bloc * HSTR + kk * 32 + grp * 8]);
    }

    // ---- fused fc epilogue ----------------------------------------------
    float v = hv * wfc;
    v += __shfl_xor(v, 4);    // eh bit 0
    v += __shfl_xor(v, 8);    // eh bit 1
    v += __shfl_xor(v, 16);   // grp bit 0
    v += __shfl_xor(v, 32);   // grp bit 1
    if (lane < 4) s_red[w * 4 + lane] = v;   // one writer per (w, bloc)
    __syncthreads();
    if (tid < 4) {
        out[b0 + tid] = s_red[tid] + s_red[4 + tid] + s_red[8 + tid]
                      + s_red[12 + tid] + b_fc[0];
    }
}

extern "C" void kernel_launch(void* const* d_in, const int* in_sizes, int n_in,
                              void* d_out, int out_size, void* d_ws, size_t ws_size,
                              hipStream_t stream) {
    const float* x    = (const float*)d_in[0];
    const float* W_ih = (const float*)d_in[1];
    const float* W_hh = (const float*)d_in[2];
    const float* b_ih = (const float*)d_in[3];
    const float* b_hh = (const float*)d_in[4];
    const float* W_fc = (const float*)d_in[5];
    const float* b_fc = (const float*)d_in[6];
    float* out = (float*)d_out;

    dim3 grid(BATCH / BB);   // 512 blocks -> 2 independent blocks per CU
    dim3 block(THREADS);     // 4 waves
    lstm_mfma2<<<grid, block, 0, stream>>>(x, W_ih, W_hh, b_ih, b_hh, W_fc, b_fc, out);
}

// Round 7
// 398.544 us; speedup vs baseline: 1.4092x; 1.4092x over previous
//
#include <hip/hip_runtime.h>

// LSTM T=1024, B=2048, INPUT=2, H=64 — MFMA recurrence.
// R6 = R4 config (256 blocks x BB=8, 4 waves, 2x column duplication, 1 wave/SIMD)
// with three latency cuts:
//  1. raw s_barrier (lgkmcnt(0) only) -> x global prefetch is NOT drained at
//     the barrier (R4/R5's __syncthreads emitted vmcnt(0) -> ~200-400 cyc/step
//     of exposed HBM/L2 latency on the serial chain).
//  2. single-bf16 W_hh (no hi/lo split): halves MFMA issue (8/wave/step).
//     W in U(+-0.125) -> bf16 step <= 2^-11, error ~ h-quant error already present.
//  3. HSTR=80 (40-dword rows): ds_read_b128 quads tile banks exactly 2-way (free).

typedef short bf16x8 __attribute__((ext_vector_type(8)));
typedef float f32x4  __attribute__((ext_vector_type(4)));

constexpr int T_STEPS = 1024;
constexpr int BATCH   = 2048;
constexpr int H       = 64;
constexpr int BB      = 8;      // batch per block
constexpr int THREADS = 256;    // 4 waves
constexpr int HSTR    = 80;     // bf16 per batch row (160 B = 40 dwords)

__device__ __forceinline__ unsigned bf16_rn(float f) {
    unsigned u = __float_as_uint(f);
    u += 0x7fffu + ((u >> 16) & 1u);
    return u >> 16;
}
__device__ __forceinline__ float sigm(float v) {
    return __builtin_amdgcn_rcpf(1.0f + __builtin_amdgcn_exp2f(v * -1.44269504f));
}
__device__ __forceinline__ float tanh_(float v) {
    return fmaf(-2.0f, __builtin_amdgcn_rcpf(1.0f + __builtin_amdgcn_exp2f(v * 2.88539008f)), 1.0f);
}
// barrier that does NOT drain vmcnt (keeps x prefetch in flight)
__device__ __forceinline__ void lds_barrier() {
    asm volatile("s_waitcnt lgkmcnt(0)" ::: "memory");
    __builtin_amdgcn_s_barrier();
}

__global__ __launch_bounds__(THREADS, 1) void lstm_mfma6(
    const float* __restrict__ x,      // (T, B, 2)
    const float* __restrict__ W_ih,   // (256, 2)
    const float* __restrict__ W_hh,   // (256, 64)
    const float* __restrict__ b_ih,   // (256)
    const float* __restrict__ b_hh,   // (256)
    const float* __restrict__ W_fc,   // (1, 64)
    const float* __restrict__ b_fc,   // (1)
    float* __restrict__ out)          // (B, 1)
{
    const int tid  = threadIdx.x;
    const int w    = tid >> 6;        // wave 0..3: h-slice [16w, 16w+16)
    const int lane = tid & 63;
    const int bcol = lane & 15;       // MFMA column
    const int grp  = lane >> 4;       // k-group / D-row group
    const int bloc = bcol & 7;        // real batch column (cols 8..15 duplicate)
    const bool elo = (bcol < 8);      // lane activates D elements {0,1} vs {2,3}

    __shared__ __align__(16) unsigned short s_ht[2][BB * HSTR]; // 2 x 1280 B
    __shared__ float s_red[32];

    const int b0 = blockIdx.x * BB;

    // ---- A fragments: gate g tile = W_hh rows [64g+16w, +16), single bf16 -
    bf16x8 Af[4][2];
    #pragma unroll
    for (int g = 0; g < 4; ++g) {
        #pragma unroll
        for (int kk = 0; kk < 2; ++kk) {
            const float* src = W_hh + (64 * g + 16 * w + bcol) * H + kk * 32 + grp * 8;
            #pragma unroll
            for (int j = 0; j < 8; ++j)
                Af[g][kk][j] = (short)bf16_rn(src[j]);
        }
    }

    // ---- gx constants: D row (gate g) = 64g + 16w + 4grp + e --------------
    float gb[4][4], c0_[4][4], c1_[4][4];
    #pragma unroll
    for (int g = 0; g < 4; ++g)
        #pragma unroll
        for (int e = 0; e < 4; ++e) {
            const int r = 64 * g + 16 * w + 4 * grp + e;
            gb[g][e]  = b_ih[r] + b_hh[r];
            c0_[g][e] = W_ih[2 * r];
            c1_[g][e] = W_ih[2 * r + 1];
        }

    // ---- per-lane state: rows rbase, rbase+1 of batch b0+bloc -------------
    const int rbase = 16 * w + 4 * grp + (elo ? 0 : 2);
    float cs0 = 0.f, cs1 = 0.f, hv0 = 0.f, hv1 = 0.f;
    const float wfc0 = W_fc[rbase];
    const float wfc1 = W_fc[rbase + 1];

    // zero both h-table buffers (2*8*80 shorts = 640 dwords)
    for (int i = tid; i < 640; i += THREADS)
        reinterpret_cast<unsigned*>(s_ht)[i] = 0;

    // ---- x: depth-3 register prefetch (dup lanes load same addr) ----------
    const float* xb = x + (b0 + bloc) * 2;
    float2 xc  = *reinterpret_cast<const float2*>(xb);
    float2 xn1 = *reinterpret_cast<const float2*>(xb + 1 * BATCH * 2);
    float2 xn2 = *reinterpret_cast<const float2*>(xb + 2 * BATCH * 2);

    __syncthreads();   // full barrier once (init visible)

    // initial B fragments from buf 0 (h = 0); single b128 per kk
    bf16x8 Bf[2];
    #pragma unroll
    for (int kk = 0; kk < 2; ++kk)
        Bf[kk] = *reinterpret_cast<const bf16x8*>(
                     &s_ht[0][bloc * HSTR + kk * 32 + grp * 8]);

    #pragma unroll 2
    for (int s = 0; s < T_STEPS; ++s) {
        // issue next x load FIRST (completes ~3 steps later; never drained)
        const int sn = (s + 3 < T_STEPS) ? s + 3 : T_STEPS - 1;
        const float2 xf = *reinterpret_cast<const float2*>(xb + sn * BATCH * 2);

        // acc init = gx (exact fp32)
        f32x4 acc[4];
        #pragma unroll
        for (int g = 0; g < 4; ++g)
            #pragma unroll
            for (int e = 0; e < 4; ++e)
                acc[g][e] = fmaf(c1_[g][e], xc.y, fmaf(c0_[g][e], xc.x, gb[g][e]));

        // recurrent GEMM: 4 gate-chains of 2 dependent MFMAs
        #pragma unroll
        for (int kk = 0; kk < 2; ++kk)
            #pragma unroll
            for (int g = 0; g < 4; ++g)
                acc[g] = __builtin_amdgcn_mfma_f32_16x16x32_bf16(Af[g][kk], Bf[kk], acc[g], 0, 0, 0);

        // select this lane's 2 states (cols duplicated -> both halves valid)
        float p[4], q[4];
        #pragma unroll
        for (int g = 0; g < 4; ++g) {
            p[g] = elo ? acc[g][0] : acc[g][2];
            q[g] = elo ? acc[g][1] : acc[g][3];
        }

        // activations + c/h update, fully in-register
        {
            const float i0 = sigm(p[0]), f0 = sigm(p[1]);
            const float g0 = tanh_(p[2]), o0 = sigm(p[3]);
            cs0 = fmaf(f0, cs0, i0 * g0);
            hv0 = o0 * tanh_(cs0);
            const float i1 = sigm(q[0]), f1 = sigm(q[1]);
            const float g1 = tanh_(q[2]), o1 = sigm(q[3]);
            cs1 = fmaf(f1, cs1, i1 * g1);
            hv1 = o1 * tanh_(cs1);
        }

        // pack 2 h -> 1 dword, write to next-parity h-table
        {
            const unsigned pk = bf16_rn(hv0) | (bf16_rn(hv1) << 16);
            *reinterpret_cast<unsigned*>(
                &s_ht[(s + 1) & 1][bloc * HSTR + rbase]) = pk;
        }

        // rotate x prefetch (depth 3)
        xc = xn1; xn1 = xn2; xn2 = xf;

        lds_barrier();   // lgkmcnt(0) + s_barrier; vmem stays in flight

        // B fragments for next step: b128 quads tile banks exactly 2-way
        #pragma unroll
        for (int kk = 0; kk < 2; ++kk)
            Bf[kk] = *reinterpret_cast<const bf16x8*>(
                         &s_ht[(s + 1) & 1][bloc * HSTR + kk * 32 + grp * 8]);
    }

    // ---- fused fc epilogue ----------------------------------------------
    float v = fmaf(hv0, wfc0, hv1 * wfc1);
    v += __shfl_xor(v, 8);    // combine e{0,1} / e{2,3} halves (same batch)
    v += __shfl_xor(v, 16);   // combine grp
    v += __shfl_xor(v, 32);
    if (lane < 8) s_red[w * 8 + lane] = v;
    __syncthreads();
    if (tid < 8) {
        out[b0 + tid] = s_red[tid] + s_red[8 + tid] + s_red[16 + tid]
                      + s_red[24 + tid] + b_fc[0];
    }
}

extern "C" void kernel_launch(void* const* d_in, const int* in_sizes, int n_in,
                              void* d_out, int out_size, void* d_ws, size_t ws_size,
                              hipStream_t stream) {
    const float* x    = (const float*)d_in[0];
    const float* W_ih = (const float*)d_in[1];
    const float* W_hh = (const float*)d_in[2];
    const float* b_ih = (const float*)d_in[3];
    const float* b_hh = (const float*)d_in[4];
    const float* W_fc = (const float*)d_in[5];
    const float* b_fc = (const float*)d_in[6];
    float* out = (float*)d_out;

    dim3 grid(BATCH / BB);   // 256 blocks -> all 256 CUs
    dim3 block(THREADS);     // 4 waves
    lstm_mfma6<<<grid, block, 0, stream>>>(x, W_ih, W_hh, b_ih, b_hh, W_fc, b_fc, out);
}